// Round 1
// baseline (367.379 us; speedup 1.0000x reference)
//
#include <hip/hip_runtime.h>
#include <hip/hip_bf16.h>
#include <stdint.h>

// NearestUpsampling (x2 nearest) + Conv2d 3x3 VALID ==
// per-output-parity 2x2 conv on the ORIGINAL input ==
// one implicit GEMM: M=16*63*63=63504, N=4par*128=512, K=128c*4=512 (bf16 MFMA).

#define B_    16
#define CIN   128
#define HIN   64
#define WIN   64
#define COUT  128
#define HO    126
#define WO    126
#define PQ    63
#define M_TOT (B_ * PQ * PQ)   // 63504
#define K_TOT 512
#define BM    128
#define BN    128
#define BK    32
#define KTILES (K_TOT / BK)    // 16
#define AS_STRIDE 40           // padded bf16 row stride (16B-aligned rows, breaks bank stride)

typedef __bf16 bf16;
typedef __bf16 bf16x8 __attribute__((ext_vector_type(8)));
typedef float  floatx4 __attribute__((ext_vector_type(4)));

// ---------------------------------------------------------------------------
// Prep: combine 3x3 weights into parity 2x2 weights, bf16, layout
// wb[(((par*16 + ktile)*128 + o)*32 + k32)]  with k = ktile*32+k32 = c*4+u*2+v
// so each GEMM K-iteration's B tile is one contiguous 8KB slab.
// ---------------------------------------------------------------------------
__global__ void prep_weights(const float* __restrict__ w, bf16* __restrict__ wb) {
    int idx = blockIdx.x * 256 + threadIdx.x;
    if (idx >= 4 * KTILES * COUT * BK) return;   // 262144
    int k32   = idx & 31;
    int o     = (idx >> 5) & 127;
    int ktile = (idx >> 12) & 15;
    int par   = idx >> 16;
    int k = ktile * 32 + k32;
    int c = k >> 2, u = (k >> 1) & 1, v = k & 1;
    int a = par >> 1, bp = par & 1;
    // tap sets: row parity a, input-row offset u -> which dy contribute
    int dy0, dy1, ndy, dx0, dx1, ndx;
    if (u == 0) { if (a == 0) { dy0 = 0; dy1 = 1; ndy = 2; } else { dy0 = 0; dy1 = 0; ndy = 1; } }
    else        { if (a == 0) { dy0 = 2; dy1 = 2; ndy = 1; } else { dy0 = 1; dy1 = 2; ndy = 2; } }
    if (v == 0) { if (bp == 0) { dx0 = 0; dx1 = 1; ndx = 2; } else { dx0 = 0; dx1 = 0; ndx = 1; } }
    else        { if (bp == 0) { dx0 = 2; dx1 = 2; ndx = 1; } else { dx0 = 1; dx1 = 2; ndx = 2; } }
    const float* wp = w + (o * CIN + c) * 9;
    float s = wp[dy0 * 3 + dx0];
    if (ndx == 2) s += wp[dy0 * 3 + dx1];
    if (ndy == 2) { s += wp[dy1 * 3 + dx0]; if (ndx == 2) s += wp[dy1 * 3 + dx1]; }
    wb[idx] = (bf16)s;
}

// ---------------------------------------------------------------------------
// Main GEMM: block = 128 M-rows x 128 Cout for one parity. 256 threads = 4 waves,
// 2x2 wave grid, each wave 64x64 via 4x4 mfma_f32_16x16x32_bf16.
// ---------------------------------------------------------------------------
__global__ __launch_bounds__(256)
void upconv_gemm(const float* __restrict__ x, const bf16* __restrict__ wb,
                 const float* __restrict__ bias, float* __restrict__ out) {
    __shared__ bf16 As[BM * AS_STRIDE];   // [m_local][k_local], padded
    __shared__ bf16 Bs[BN * BK];          // [o][k_local], linear (matches wb slab order)

    const int t    = threadIdx.x;
    const int lane = t & 63;
    const int wid  = t >> 6;
    const int wm   = wid >> 1, wn = wid & 1;
    const int quad = lane >> 4;
    const int l15  = lane & 15;
    const int kq   = quad * 8;

    const int mtile = blockIdx.x;
    const int par   = blockIdx.y;
    const int a     = par >> 1, bp = par & 1;
    const int m0    = mtile * BM;

    // --- per-thread A-staging coords (fixed m, 16 consecutive k per iter) ---
    const int ml = t & 127;
    const int hi = t >> 7;                // k half: k_local in [hi*16, hi*16+16)
    const int m_mine = m0 + ml;
    const bool mvalid = (m_mine < M_TOT);
    int b_ = 0, p_ = 0, q_ = 0;
    if (mvalid) { b_ = m_mine / 3969; int rr = m_mine - b_ * 3969; p_ = rr / 63; q_ = rr - p_ * 63; }
    const float* xbase = x + ((size_t)(b_ * CIN) * HIN + p_) * WIN + q_;

    const bf16* wslab = wb + (size_t)par * (KTILES * BN * BK);

    floatx4 acc[4][4] = {};

    for (int kt = 0; kt < KTILES; ++kt) {
        __syncthreads();
        // ---- stage B: contiguous 8KB copy (coalesced, conflict-free) ----
        {
            const uint4* src = (const uint4*)(wslab + kt * (BN * BK));
            uint4* dst = (uint4*)Bs;
            dst[t]       = src[t];
            dst[t + 256] = src[t + 256];
        }
        // ---- stage A: gather fp32 -> bf16, 4 x (2x2 taps) per thread ----
        {
            const int kk = kt * BK;
            #pragma unroll
            for (int cl = 0; cl < 4; ++cl) {
                const int c = (kk >> 2) + hi * 4 + cl;
                float f00 = 0.f, f01 = 0.f, f10 = 0.f, f11 = 0.f;
                if (mvalid) {
                    const float* pa = xbase + (size_t)c * (HIN * WIN);
                    f00 = pa[0]; f01 = pa[1]; f10 = pa[WIN]; f11 = pa[WIN + 1];
                }
                bf16* wptr = &As[ml * AS_STRIDE + hi * 16 + cl * 4];
                wptr[0] = (bf16)f00;  // k = c*4 + 0  (u=0,v=0)
                wptr[1] = (bf16)f01;  // k = c*4 + 1  (u=0,v=1)
                wptr[2] = (bf16)f10;  // k = c*4 + 2  (u=1,v=0)
                wptr[3] = (bf16)f11;  // k = c*4 + 3  (u=1,v=1)
            }
        }
        __syncthreads();
        // ---- MFMA: 8 ds_read_b128 + 16 MFMA per wave per iter ----
        bf16x8 af[4], bfr[4];
        #pragma unroll
        for (int i = 0; i < 4; ++i) {
            af[i]  = *(const bf16x8*)&As[(wm * 64 + i * 16 + l15) * AS_STRIDE + kq];
            bfr[i] = *(const bf16x8*)&Bs[(wn * 64 + i * 16 + l15) * BK + kq];
        }
        #pragma unroll
        for (int mt = 0; mt < 4; ++mt)
            #pragma unroll
            for (int nt = 0; nt < 4; ++nt)
                acc[mt][nt] = __builtin_amdgcn_mfma_f32_16x16x32_bf16(af[mt], bfr[nt], acc[mt][nt], 0, 0, 0);
    }

    // ---- epilogue: C/D layout col = lane&15 (-> o), row = quad*4 + ri (-> m) ----
    float bv[4];
    #pragma unroll
    for (int nt = 0; nt < 4; ++nt) bv[nt] = bias[wn * 64 + nt * 16 + l15];

    #pragma unroll
    for (int mt = 0; mt < 4; ++mt) {
        #pragma unroll
        for (int ri = 0; ri < 4; ++ri) {
            const int m = m0 + wm * 64 + mt * 16 + quad * 4 + ri;
            if (m >= M_TOT) continue;
            const int b = m / 3969; const int rr = m - b * 3969;
            const int p = rr / 63;  const int q = rr - p * 63;
            float* op = out + ((size_t)(b * COUT) * HO + (2 * p + a)) * WO + (2 * q + bp);
            #pragma unroll
            for (int nt = 0; nt < 4; ++nt) {
                const int o = wn * 64 + nt * 16 + l15;
                op[(size_t)o * (HO * WO)] = acc[mt][nt][ri] + bv[nt];
            }
        }
    }
}

extern "C" void kernel_launch(void* const* d_in, const int* in_sizes, int n_in,
                              void* d_out, int out_size, void* d_ws, size_t ws_size,
                              hipStream_t stream) {
    const float* x    = (const float*)d_in[0];
    const float* w    = (const float*)d_in[1];
    const float* bias = (const float*)d_in[2];
    float* out = (float*)d_out;
    bf16* wb = (bf16*)d_ws;   // needs 512 KB

    prep_weights<<<(4 * KTILES * COUT * BK + 255) / 256, 256, 0, stream>>>(w, wb);

    dim3 grid((M_TOT + BM - 1) / BM, 4);   // 497 M-tiles x 4 parities
    upconv_gemm<<<grid, 256, 0, stream>>>(x, wb, bias, out);
}

// Round 2
// 273.138 us; speedup vs baseline: 1.3450x; 1.3450x over previous
//
#include <hip/hip_runtime.h>
#include <hip/hip_bf16.h>
#include <stdint.h>

// NearestUpsampling (x2) + 3x3 VALID conv == per-parity 2x2 conv on original x
// == implicit GEMM M=16*63*63=63504, N=(4 par)*(128 Cout), K=128c*4taps=512.
// R2: one block = 64 M-rows x 128 Cout x ALL 4 parities (A staged once),
//     LDS-transposed epilogue -> coalesced float2 row writes (both W-parities).

#define B_    16
#define CIN   128
#define HIN   64
#define WIN   64
#define COUT  128
#define HO    126
#define WO    126
#define M_TOT (B_ * 63 * 63)   // 63504
#define BM    64
#define BK    32
#define KTILES 16
#define AS_STRIDE 40           // bf16 units, rows 16B-aligned
#define ES_STRIDE 35           // float units, epilogue pad

typedef __bf16 bf16;
typedef __bf16 bf16x4 __attribute__((ext_vector_type(4)));
typedef __bf16 bf16x8 __attribute__((ext_vector_type(8)));
typedef float  floatx4 __attribute__((ext_vector_type(4)));

// ---------------------------------------------------------------------------
// Prep: combine 3x3 weights into parity 2x2 weights (bf16).
// Layout: wb[(((kt*4 + par)*128 + o)*32 + k32)], k = kt*32+k32 = c*4 + u*2 + v.
// One K-step's B tile (all 4 parities) = contiguous 32 KB slab.
// ---------------------------------------------------------------------------
__global__ void prep_weights(const float* __restrict__ w, bf16* __restrict__ wb) {
    int idx = blockIdx.x * 256 + threadIdx.x;
    if (idx >= 4 * KTILES * COUT * BK) return;   // 262144
    int k32 = idx & 31;
    int o   = (idx >> 5) & 127;
    int par = (idx >> 12) & 3;
    int kt  = idx >> 14;
    int k = kt * 32 + k32;
    int c = k >> 2, u = (k >> 1) & 1, v = k & 1;
    int a = par >> 1, bp = par & 1;
    int dy0, dy1, ndy, dx0, dx1, ndx;
    if (u == 0) { if (a == 0) { dy0 = 0; dy1 = 1; ndy = 2; } else { dy0 = 0; dy1 = 0; ndy = 1; } }
    else        { if (a == 0) { dy0 = 2; dy1 = 2; ndy = 1; } else { dy0 = 1; dy1 = 2; ndy = 2; } }
    if (v == 0) { if (bp == 0) { dx0 = 0; dx1 = 1; ndx = 2; } else { dx0 = 0; dx1 = 0; ndx = 1; } }
    else        { if (bp == 0) { dx0 = 2; dx1 = 2; ndx = 1; } else { dx0 = 1; dx1 = 2; ndx = 2; } }
    const float* wp = w + (o * CIN + c) * 9;
    float s = wp[dy0 * 3 + dx0];
    if (ndx == 2) s += wp[dy0 * 3 + dx1];
    if (ndy == 2) { s += wp[dy1 * 3 + dx0]; if (ndx == 2) s += wp[dy1 * 3 + dx1]; }
    wb[idx] = (bf16)s;
}

// ---------------------------------------------------------------------------
// Main kernel. 512 threads = 8 waves. Wave wid: parity wp = wid>>1, N-half
// wn = wid&1. Each wave: 64 M x 64 o via 4x4 mfma_f32_16x16x32_bf16.
// ---------------------------------------------------------------------------
__global__ __launch_bounds__(512)
void upconv_gemm(const float* __restrict__ x, const bf16* __restrict__ wb,
                 const float* __restrict__ bias, float* __restrict__ out) {
    __shared__ union {
        struct { bf16 As[BM * AS_STRIDE]; bf16 Bs[4 * COUT * BK]; } k;  // 5120 + 32768 B
        float E[4 * BM * ES_STRIDE];                                    // 35840 B
    } lds;

    const int t    = threadIdx.x;
    const int lane = t & 63;
    const int wid  = t >> 6;
    const int wp   = wid >> 1;          // wave's parity (a*2 + bp)
    const int wn   = wid & 1;           // o half
    const int quad = lane >> 4;
    const int l15  = lane & 15;
    const int kq   = quad * 8;

    const int m0 = blockIdx.x * BM;

    // --- A-staging coords: thread handles m-row (t&63), channel offset (t>>6) ---
    const int ml = t & 63;
    const int m_mine = m0 + ml;
    const bool mvalid = (m_mine < M_TOT);
    int b_ = 0, p_ = 0, q_ = 0;
    if (mvalid) { b_ = m_mine / 3969; int rr = m_mine - b_ * 3969; p_ = rr / 63; q_ = rr - p_ * 63; }
    const float* xbase = x + ((size_t)(b_ * CIN) * HIN + p_) * WIN + q_;

    floatx4 acc[4][4] = {};

    for (int kt = 0; kt < KTILES; ++kt) {
        __syncthreads();
        // ---- stage B: one contiguous 32 KB slab (all 4 parities) ----
        {
            const uint4* src = (const uint4*)(wb + (size_t)kt * (4 * COUT * BK));
            uint4* dst = (uint4*)lds.k.Bs;
            #pragma unroll
            for (int i = 0; i < 4; ++i) dst[t + i * 512] = src[t + i * 512];
        }
        // ---- stage A: gather 2x2 taps fp32 -> bf16 (shared by all parities) ----
        {
            const int c = kt * 8 + wid;
            float f00 = 0.f, f01 = 0.f, f10 = 0.f, f11 = 0.f;
            if (mvalid) {
                const float* pa = xbase + (size_t)c * (HIN * WIN);
                f00 = pa[0]; f01 = pa[1]; f10 = pa[WIN]; f11 = pa[WIN + 1];
            }
            bf16x4 v; v[0] = (bf16)f00; v[1] = (bf16)f01; v[2] = (bf16)f10; v[3] = (bf16)f11;
            *(bf16x4*)&lds.k.As[ml * AS_STRIDE + wid * 4] = v;   // k_local = (c-kt*8)*4 + tap
        }
        __syncthreads();
        // ---- fragments + MFMA ----
        bf16x8 af[4], bfr[4];
        #pragma unroll
        for (int i = 0; i < 4; ++i) {
            af[i]  = *(const bf16x8*)&lds.k.As[(i * 16 + l15) * AS_STRIDE + kq];
            bfr[i] = *(const bf16x8*)&lds.k.Bs[wp * (COUT * BK) + (wn * 64 + i * 16 + l15) * BK + kq];
        }
        #pragma unroll
        for (int mt = 0; mt < 4; ++mt)
            #pragma unroll
            for (int nt = 0; nt < 4; ++nt)
                acc[mt][nt] = __builtin_amdgcn_mfma_f32_16x16x32_bf16(af[mt], bfr[nt], acc[mt][nt], 0, 0, 0);
    }

    // ---- epilogue: LDS transpose -> coalesced float2 writes (bp pair) ----
    float bv[4];
    #pragma unroll
    for (int nt = 0; nt < 4; ++nt) bv[nt] = bias[wn * 64 + nt * 16 + l15];

    const int o_idx = t >> 4;    // 0..31 within chunk
    const int ml16  = t & 15;

    #pragma unroll
    for (int j = 0; j < 4; ++j) {           // o-chunk j: global o = j*32 + oc
        __syncthreads();
        if (wn == (j >> 1)) {
            const int nt0 = (j & 1) * 2;
            #pragma unroll
            for (int dn = 0; dn < 2; ++dn) {
                const int nt = nt0 + dn;
                #pragma unroll
                for (int mt = 0; mt < 4; ++mt)
                    #pragma unroll
                    for (int ri = 0; ri < 4; ++ri)
                        lds.E[(wp * BM + mt * 16 + quad * 4 + ri) * ES_STRIDE + dn * 16 + l15]
                            = acc[mt][nt][ri] + bv[nt];
            }
        }
        __syncthreads();
        // stage 2: lanes along m (q), both W-parities per thread -> float2
        #pragma unroll
        for (int it = 0; it < 4; ++it) {
            const int mm = it * 16 + ml16;
            const int m  = m0 + mm;
            if (m >= M_TOT) continue;
            const int b = m / 3969; const int rr = m - b * 3969;
            const int p = rr / 63;  const int q = rr - p * 63;
            const int o = j * 32 + o_idx;
            #pragma unroll
            for (int a = 0; a < 2; ++a) {
                const float f0 = lds.E[((a * 2 + 0) * BM + mm) * ES_STRIDE + o_idx];
                const float f1 = lds.E[((a * 2 + 1) * BM + mm) * ES_STRIDE + o_idx];
                float* op = out + (((size_t)(b * COUT + o)) * HO + (2 * p + a)) * WO + 2 * q;
                *(float2*)op = make_float2(f0, f1);
            }
        }
    }
}

extern "C" void kernel_launch(void* const* d_in, const int* in_sizes, int n_in,
                              void* d_out, int out_size, void* d_ws, size_t ws_size,
                              hipStream_t stream) {
    const float* x    = (const float*)d_in[0];
    const float* w    = (const float*)d_in[1];
    const float* bias = (const float*)d_in[2];
    float* out = (float*)d_out;
    bf16* wb = (bf16*)d_ws;   // 512 KB

    prep_weights<<<(4 * KTILES * COUT * BK + 255) / 256, 256, 0, stream>>>(w, wb);

    dim3 grid((M_TOT + BM - 1) / BM);   // 993 blocks, all parities per block
    upconv_gemm<<<grid, 512, 0, stream>>>(x, wb, bias, out);
}

// Round 3
// 219.337 us; speedup vs baseline: 1.6749x; 1.2453x over previous
//
#include <hip/hip_runtime.h>
#include <hip/hip_bf16.h>
#include <stdint.h>

// NearestUpsampling (x2) + 3x3 VALID conv == per-parity 2x2 conv on original x
// == implicit GEMM M=16*63*63=63504, N=(4 par)*(128 Cout), K=128c*4taps=512.
// R3: swapped MFMA operands (D = W . Act^T) so lanes run along m (=q):
//     both W-parities held per lane -> coalesced float2 stores, NO epilogue LDS.

#define B_    16
#define CIN   128
#define HIN   64
#define WIN   64
#define COUT  128
#define HO    126
#define WO    126
#define M_TOT (B_ * 63 * 63)   // 63504
#define BM    64
#define BK    32
#define KTILES 16
#define AS_STRIDE 40           // bf16 units, rows 16B-aligned

typedef __bf16 bf16;
typedef __bf16 bf16x4 __attribute__((ext_vector_type(4)));
typedef __bf16 bf16x8 __attribute__((ext_vector_type(8)));
typedef float  floatx4 __attribute__((ext_vector_type(4)));

// ---------------------------------------------------------------------------
// Prep: combine 3x3 weights into parity 2x2 weights (bf16).
// Layout: wb[(((kt*4 + par)*128 + o)*32 + k32)], k = kt*32+k32 = c*4 + u*2 + v.
// One K-step's B tile (all 4 parities) = contiguous 32 KB slab.
// ---------------------------------------------------------------------------
__global__ void prep_weights(const float* __restrict__ w, bf16* __restrict__ wb) {
    int idx = blockIdx.x * 256 + threadIdx.x;
    if (idx >= 4 * KTILES * COUT * BK) return;   // 262144
    int k32 = idx & 31;
    int o   = (idx >> 5) & 127;
    int par = (idx >> 12) & 3;
    int kt  = idx >> 14;
    int k = kt * 32 + k32;
    int c = k >> 2, u = (k >> 1) & 1, v = k & 1;
    int a = par >> 1, bp = par & 1;
    int dy0, dy1, ndy, dx0, dx1, ndx;
    if (u == 0) { if (a == 0) { dy0 = 0; dy1 = 1; ndy = 2; } else { dy0 = 0; dy1 = 0; ndy = 1; } }
    else        { if (a == 0) { dy0 = 2; dy1 = 2; ndy = 1; } else { dy0 = 1; dy1 = 2; ndy = 2; } }
    if (v == 0) { if (bp == 0) { dx0 = 0; dx1 = 1; ndx = 2; } else { dx0 = 0; dx1 = 0; ndx = 1; } }
    else        { if (bp == 0) { dx0 = 2; dx1 = 2; ndx = 1; } else { dx0 = 1; dx1 = 2; ndx = 2; } }
    const float* wp = w + (o * CIN + c) * 9;
    float s = wp[dy0 * 3 + dx0];
    if (ndx == 2) s += wp[dy0 * 3 + dx1];
    if (ndy == 2) { s += wp[dy1 * 3 + dx0]; if (ndx == 2) s += wp[dy1 * 3 + dx1]; }
    wb[idx] = (bf16)s;
}

// ---------------------------------------------------------------------------
// Main kernel. 512 threads = 8 waves. Wave wid: a = wid>>2 (row parity),
// oq = wid&3 (o-quarter, 32 Couts). Each wave: 32 o x 64 m x both bp parities
// via mfma(wf, af, acc) -> D[row=o][col=m].
// ---------------------------------------------------------------------------
__global__ __launch_bounds__(512)
void upconv_gemm(const float* __restrict__ x, const bf16* __restrict__ wb,
                 const float* __restrict__ bias, float* __restrict__ out) {
    __shared__ bf16 As[BM * AS_STRIDE];      // [m_local][k_local], padded
    __shared__ bf16 Bs[4 * COUT * BK];       // [par][o][k_local], linear

    const int t    = threadIdx.x;
    const int lane = t & 63;
    const int wid  = t >> 6;
    const int a    = wid >> 2;          // output-row parity
    const int oq   = wid & 3;           // o-quarter
    const int quad = lane >> 4;
    const int l15  = lane & 15;
    const int kq   = quad * 8;

    const int m0 = blockIdx.x * BM;

    // --- A-staging coords: thread handles m-row (t&63), channel (t>>6) ---
    const int ml = t & 63;
    const int m_mine = m0 + ml;
    const bool mvalid = (m_mine < M_TOT);
    int b_ = 0, p_ = 0, q_ = 0;
    if (mvalid) { b_ = m_mine / 3969; int rr = m_mine - b_ * 3969; p_ = rr / 63; q_ = rr - p_ * 63; }
    const float* xbase = x + ((size_t)(b_ * CIN) * HIN + p_) * WIN + q_;

    floatx4 acc[2][4][2] = {};   // [bp][mt][nt]

    for (int kt = 0; kt < KTILES; ++kt) {
        __syncthreads();
        // ---- stage B: one contiguous 32 KB slab (all 4 parities) ----
        {
            const uint4* src = (const uint4*)(wb + (size_t)kt * (4 * COUT * BK));
            uint4* dst = (uint4*)Bs;
            #pragma unroll
            for (int i = 0; i < 4; ++i) dst[t + i * 512] = src[t + i * 512];
        }
        // ---- stage A: gather 2x2 taps fp32 -> bf16 (shared by all parities) ----
        {
            const int c = kt * 8 + wid;
            float f00 = 0.f, f01 = 0.f, f10 = 0.f, f11 = 0.f;
            if (mvalid) {
                const float* pa = xbase + (size_t)c * (HIN * WIN);
                f00 = pa[0]; f01 = pa[1]; f10 = pa[WIN]; f11 = pa[WIN + 1];
            }
            bf16x4 v; v[0] = (bf16)f00; v[1] = (bf16)f01; v[2] = (bf16)f10; v[3] = (bf16)f11;
            *(bf16x4*)&As[ml * AS_STRIDE + wid * 4] = v;   // k_local = (c-kt*8)*4 + tap
        }
        __syncthreads();
        // ---- fragments + MFMA (operands swapped: weights are A-operand) ----
        bf16x8 af[4], wf[2][2];
        #pragma unroll
        for (int i = 0; i < 4; ++i)
            af[i] = *(const bf16x8*)&As[(i * 16 + l15) * AS_STRIDE + kq];
        #pragma unroll
        for (int bp = 0; bp < 2; ++bp)
            #pragma unroll
            for (int nt = 0; nt < 2; ++nt)
                wf[bp][nt] = *(const bf16x8*)&Bs[(a * 2 + bp) * (COUT * BK)
                                                + (oq * 32 + nt * 16 + l15) * BK + kq];
        #pragma unroll
        for (int bp = 0; bp < 2; ++bp)
            #pragma unroll
            for (int mt = 0; mt < 4; ++mt)
                #pragma unroll
                for (int nt = 0; nt < 2; ++nt)
                    acc[bp][mt][nt] = __builtin_amdgcn_mfma_f32_16x16x32_bf16(
                        wf[bp][nt], af[mt], acc[bp][mt][nt], 0, 0, 0);
    }

    // ---- epilogue: direct coalesced float2 stores (no LDS) ----
    // D layout: col = lane&15 -> m, row = quad*4+ri -> o (within 16-tile).
    float bv[2][4];
    #pragma unroll
    for (int nt = 0; nt < 2; ++nt)
        #pragma unroll
        for (int ri = 0; ri < 4; ++ri)
            bv[nt][ri] = bias[oq * 32 + nt * 16 + quad * 4 + ri];

    #pragma unroll
    for (int mt = 0; mt < 4; ++mt) {
        const int m = m0 + mt * 16 + l15;
        const bool v = (m < M_TOT);
        int b = 0, p = 0, q = 0;
        if (v) { b = m / 3969; int rr = m - b * 3969; p = rr / 63; q = rr - p * 63; }
        float* base = out + (size_t)b * (COUT * HO * WO) + (size_t)(2 * p + a) * WO + 2 * q;
        #pragma unroll
        for (int nt = 0; nt < 2; ++nt) {
            #pragma unroll
            for (int ri = 0; ri < 4; ++ri) {
                const int o = oq * 32 + nt * 16 + quad * 4 + ri;
                if (v) {
                    float2 r = make_float2(acc[0][mt][nt][ri] + bv[nt][ri],
                                           acc[1][mt][nt][ri] + bv[nt][ri]);
                    *(float2*)(base + (size_t)o * (HO * WO)) = r;
                }
            }
        }
    }
}

extern "C" void kernel_launch(void* const* d_in, const int* in_sizes, int n_in,
                              void* d_out, int out_size, void* d_ws, size_t ws_size,
                              hipStream_t stream) {
    const float* x    = (const float*)d_in[0];
    const float* w    = (const float*)d_in[1];
    const float* bias = (const float*)d_in[2];
    float* out = (float*)d_out;
    bf16* wb = (bf16*)d_ws;   // 512 KB

    prep_weights<<<(4 * KTILES * COUT * BK + 255) / 256, 256, 0, stream>>>(w, wb);

    dim3 grid((M_TOT + BM - 1) / BM);   // 993 blocks, all parities per block
    upconv_gemm<<<grid, 512, 0, stream>>>(x, wb, bias, out);
}

// Round 4
// 217.211 us; speedup vs baseline: 1.6913x; 1.0098x over previous
//
#include <hip/hip_runtime.h>
#include <hip/hip_bf16.h>
#include <stdint.h>

// NearestUpsampling (x2) + 3x3 VALID conv == per-parity 2x2 conv on original x
// == implicit GEMM M=16*63*63=63504, N=(4 par)*(128 Cout), K=128c*4taps=512.
// R4: whole A-tile (64 x 512, 65KB) staged in LDS ONCE -> K-loop has ZERO
//     barriers; W fragments loaded straight from global (L2-resident, layout
//     is fragment-linear) -> no B staging, no Bs bank conflicts.

#define B_    16
#define CIN   128
#define HIN   64
#define WIN   64
#define COUT  128
#define HO    126
#define WO    126
#define M_TOT (B_ * 63 * 63)   // 63504
#define BM    64
#define KTILES 16
#define AS_K  520              // bf16 row stride: 1040 B (16B-aligned, bank-spread)

typedef __bf16 bf16;
typedef __bf16 bf16x4 __attribute__((ext_vector_type(4)));
typedef __bf16 bf16x8 __attribute__((ext_vector_type(8)));
typedef float  floatx4 __attribute__((ext_vector_type(4)));

// ---------------------------------------------------------------------------
// Prep: combine 3x3 weights into parity 2x2 weights (bf16).
// Layout: wb[(((kt*4 + par)*128 + o)*32 + k32)], k = kt*32+k32 = c*4 + u*2 + v.
// A wave's (par,o,quad) MFMA fragment is a contiguous 16B run of this array.
// ---------------------------------------------------------------------------
__global__ void prep_weights(const float* __restrict__ w, bf16* __restrict__ wb) {
    int idx = blockIdx.x * 256 + threadIdx.x;
    if (idx >= 4 * KTILES * COUT * 32) return;   // 262144
    int k32 = idx & 31;
    int o   = (idx >> 5) & 127;
    int par = (idx >> 12) & 3;
    int kt  = idx >> 14;
    int k = kt * 32 + k32;
    int c = k >> 2, u = (k >> 1) & 1, v = k & 1;
    int a = par >> 1, bp = par & 1;
    int dy0, dy1, ndy, dx0, dx1, ndx;
    if (u == 0) { if (a == 0) { dy0 = 0; dy1 = 1; ndy = 2; } else { dy0 = 0; dy1 = 0; ndy = 1; } }
    else        { if (a == 0) { dy0 = 2; dy1 = 2; ndy = 1; } else { dy0 = 1; dy1 = 2; ndy = 2; } }
    if (v == 0) { if (bp == 0) { dx0 = 0; dx1 = 1; ndx = 2; } else { dx0 = 0; dx1 = 0; ndx = 1; } }
    else        { if (bp == 0) { dx0 = 2; dx1 = 2; ndx = 1; } else { dx0 = 1; dx1 = 2; ndx = 2; } }
    const float* wp = w + (o * CIN + c) * 9;
    float s = wp[dy0 * 3 + dx0];
    if (ndx == 2) s += wp[dy0 * 3 + dx1];
    if (ndy == 2) { s += wp[dy1 * 3 + dx0]; if (ndx == 2) s += wp[dy1 * 3 + dx1]; }
    wb[idx] = (bf16)s;
}

// ---------------------------------------------------------------------------
// Main kernel. 512 threads = 8 waves: a = wid>>2 (row parity), oq = wid&3
// (o-quarter). Wave: 32 o x 64 m x both bp via mfma(wf, af) -> D[row=o][col=m].
// ---------------------------------------------------------------------------
__global__ __launch_bounds__(512, 4)
void upconv_gemm(const float* __restrict__ x, const bf16* __restrict__ wb,
                 const float* __restrict__ bias, float* __restrict__ out) {
    __shared__ bf16 As[BM * AS_K];   // 66560 B: [m_local][k], whole K

    const int t    = threadIdx.x;
    const int lane = t & 63;
    const int wid  = t >> 6;
    const int a    = wid >> 2;          // output-row parity
    const int oq   = wid & 3;           // o-quarter
    const int quad = lane >> 4;
    const int l15  = lane & 15;
    const int kq   = quad * 8;

    const int m0 = blockIdx.x * BM;

    // --- stage the ENTIRE A tile (all 512 k) once ---
    const int ml = lane;                // m-row handled by this thread
    const int m_mine = m0 + ml;
    const bool mvalid = (m_mine < M_TOT);
    int b_ = 0, p_ = 0, q_ = 0;
    if (mvalid) { b_ = m_mine / 3969; int rr = m_mine - b_ * 3969; p_ = rr / 63; q_ = rr - p_ * 63; }
    const float* xbase = x + ((size_t)(b_ * CIN) * HIN + p_) * WIN + q_;

    #pragma unroll
    for (int cc = 0; cc < 16; ++cc) {
        const int c = wid * 16 + cc;    // channel: wave covers 16 channels
        float f00 = 0.f, f01 = 0.f, f10 = 0.f, f11 = 0.f;
        if (mvalid) {
            const float* pa = xbase + (size_t)c * (HIN * WIN);
            f00 = pa[0]; f01 = pa[1]; f10 = pa[WIN]; f11 = pa[WIN + 1];
        }
        bf16x4 v; v[0] = (bf16)f00; v[1] = (bf16)f01; v[2] = (bf16)f10; v[3] = (bf16)f11;
        *(bf16x4*)&As[ml * AS_K + c * 4] = v;   // k = c*4 + tap
    }
    __syncthreads();   // the ONLY barrier

    // --- K-loop: no barriers, wf straight from global (L2-resident) ---
    const bf16* wwave = wb + ((size_t)(a * 2) * COUT + oq * 32 + l15) * 32 + kq;

    floatx4 acc[2][4][2] = {};   // [bp][mt][nt]

    #pragma unroll
    for (int kt = 0; kt < KTILES; ++kt) {
        bf16x8 af[4], wf[2][2];
        #pragma unroll
        for (int i = 0; i < 4; ++i)
            af[i] = *(const bf16x8*)&As[(i * 16 + l15) * AS_K + kt * 32 + kq];
        #pragma unroll
        for (int bp = 0; bp < 2; ++bp)
            #pragma unroll
            for (int nt = 0; nt < 2; ++nt)
                wf[bp][nt] = *(const bf16x8*)(wwave
                    + ((size_t)kt * 4 * COUT + (size_t)bp * COUT + nt * 16) * 32);
        #pragma unroll
        for (int bp = 0; bp < 2; ++bp)
            #pragma unroll
            for (int mt = 0; mt < 4; ++mt)
                #pragma unroll
                for (int nt = 0; nt < 2; ++nt)
                    acc[bp][mt][nt] = __builtin_amdgcn_mfma_f32_16x16x32_bf16(
                        wf[bp][nt], af[mt], acc[bp][mt][nt], 0, 0, 0);
    }

    // ---- epilogue: direct coalesced float2 stores (no LDS) ----
    // D layout: col = lane&15 -> m, row = quad*4+ri -> o (within 16-tile).
    float bv[2][4];
    #pragma unroll
    for (int nt = 0; nt < 2; ++nt)
        #pragma unroll
        for (int ri = 0; ri < 4; ++ri)
            bv[nt][ri] = bias[oq * 32 + nt * 16 + quad * 4 + ri];

    #pragma unroll
    for (int mt = 0; mt < 4; ++mt) {
        const int m = m0 + mt * 16 + l15;
        const bool v = (m < M_TOT);
        int b = 0, p = 0, q = 0;
        if (v) { b = m / 3969; int rr = m - b * 3969; p = rr / 63; q = rr - p * 63; }
        float* base = out + (size_t)b * (COUT * HO * WO) + (size_t)(2 * p + a) * WO + 2 * q;
        #pragma unroll
        for (int nt = 0; nt < 2; ++nt) {
            #pragma unroll
            for (int ri = 0; ri < 4; ++ri) {
                const int o = oq * 32 + nt * 16 + quad * 4 + ri;
                if (v) {
                    float2 r = make_float2(acc[0][mt][nt][ri] + bv[nt][ri],
                                           acc[1][mt][nt][ri] + bv[nt][ri]);
                    *(float2*)(base + (size_t)o * (HO * WO)) = r;
                }
            }
        }
    }
}

extern "C" void kernel_launch(void* const* d_in, const int* in_sizes, int n_in,
                              void* d_out, int out_size, void* d_ws, size_t ws_size,
                              hipStream_t stream) {
    const float* x    = (const float*)d_in[0];
    const float* w    = (const float*)d_in[1];
    const float* bias = (const float*)d_in[2];
    float* out = (float*)d_out;
    bf16* wb = (bf16*)d_ws;   // 512 KB

    prep_weights<<<(4 * KTILES * COUT * 32 + 255) / 256, 256, 0, stream>>>(w, wb);

    dim3 grid((M_TOT + BM - 1) / BM);   // 993 blocks
    upconv_gemm<<<grid, 512, 0, stream>>>(x, wb, bias, out);
}